// Round 3
// baseline (820.334 us; speedup 1.0000x reference)
//
#include <hip/hip_runtime.h>
#include <hip/hip_bf16.h>

// LSTM: B=512, T=4096, I=1, H=16, O=1. f32 in/out.
// R2: TWO batch elements per wave (dual independent recurrence chains).
// Lane l: gate k=l&3 (i,f,g,o), unit j=l>>2, row r=16k+j — same mapping for
// both batches, so wrow/wx/wb weights are shared. The two chains interleave
// in the SIMD issue slots, hiding each other's trans/DPP/readlane latency.

constexpr int NB = 512;   // batch
constexpr int NT = 4096;  // timesteps

template<int CTRL>
__device__ __forceinline__ float qbcast(float x) {
  return __int_as_float(__builtin_amdgcn_mov_dpp(__float_as_int(x), CTRL, 0xF, 0xF, true));
}
__device__ __forceinline__ float rdlane(float x, int lane) {
  return __int_as_float(__builtin_amdgcn_readlane(__float_as_int(x), lane));
}
__device__ __forceinline__ float vexp2(float x) {
  float r; asm("v_exp_f32 %0, %1" : "=v"(r) : "v"(x)); return r;
}
__device__ __forceinline__ float vrcp(float x) {
  float r; asm("v_rcp_f32 %0, %1" : "=v"(r) : "v"(x)); return r;
}

__global__ __launch_bounds__(64, 1) void lstm_fused(
    const float* __restrict__ x,     // [B, T]
    const float* __restrict__ W_ih,  // [64, 1]
    const float* __restrict__ W_hh,  // [64, 16]
    const float* __restrict__ b_ih,  // [64]
    const float* __restrict__ b_hh,  // [64]
    const float* __restrict__ W_fc,  // [1, 16]
    const float* __restrict__ b_fc,  // [1]
    float* __restrict__ out)         // [B, T]
{
  __shared__ float tile0[64 * 65];   // [t%64][lane], stride 65: conflict-free
  __shared__ float tile1[64 * 65];
  const int b0 = blockIdx.x * 2;
  const int b1 = b0 + 1;
  const int l = threadIdx.x;
  const int j = l >> 2;
  const int k = l & 3;               // 0=i 1=f 2=g 3=o
  const int r = k * 16 + j;

  constexpr float LOG2E = 1.4426950408889634f;
  constexpr float K2    = -2.0f * LOG2E;       // cs = K2 * c
  const float sc = (k == 2) ? K2 : -LOG2E;

  float wrow[16];
  #pragma unroll
  for (int q = 0; q < 16; ++q) wrow[q] = W_hh[r * 16 + q] * sc;
  const float wx    = W_ih[r] * sc;
  const float wb    = (b_ih[r] + b_hh[r]) * sc;
  const float act_m = (k == 2) ? (2.0f * K2) : 1.0f;
  const float act_a = (k == 2) ? (-K2)       : 0.0f;
  const float wfc   = W_fc[j] * 0.25f;
  const float bfc   = b_fc[0];

  const float* xb0 = x + (size_t)b0 * NT;
  const float* xb1 = x + (size_t)b1 * NT;
  float*       ob0 = out + (size_t)b0 * NT;
  float*       ob1 = out + (size_t)b1 * NT;

  float cs0 = 0.0f, cs1 = 0.0f;
  float sh0[16], sh1[16];
  #pragma unroll
  for (int q = 0; q < 16; ++q) { sh0[q] = 0.0f; sh1[q] = 0.0f; }

  float xcur0 = xb0[l];
  float xcur1 = xb1[l];

  for (int blk = 0; blk < NT / 64; ++blk) {
    float xnext0 = 0.0f, xnext1 = 0.0f;
    if (blk + 1 < NT / 64) {
      xnext0 = xb0[(blk + 1) * 64 + l];
      xnext1 = xb1[(blk + 1) * 64 + l];
    }

    #pragma unroll 8
    for (int tt = 0; tt < 64; ++tt) {
      const float sx0    = rdlane(xcur0, tt);
      const float sx1    = rdlane(xcur1, tt);
      const float xinit0 = fmaf(wx, sx0, wb);
      const float xinit1 = fmaf(wx, sx1, wb);

      float a00 = fmaf(wrow[0], sh0[0], xinit0);
      float a10 = fmaf(wrow[0], sh1[0], xinit1);
      float a01 = wrow[1] * sh0[1];
      float a11 = wrow[1] * sh1[1];
      float a02 = wrow[2] * sh0[2];
      float a12 = wrow[2] * sh1[2];
      float a03 = wrow[3] * sh0[3];
      float a13 = wrow[3] * sh1[3];
      #pragma unroll
      for (int q = 4; q < 16; q += 4) {
        a00 = fmaf(wrow[q + 0], sh0[q + 0], a00);
        a10 = fmaf(wrow[q + 0], sh1[q + 0], a10);
        a01 = fmaf(wrow[q + 1], sh0[q + 1], a01);
        a11 = fmaf(wrow[q + 1], sh1[q + 1], a11);
        a02 = fmaf(wrow[q + 2], sh0[q + 2], a02);
        a12 = fmaf(wrow[q + 2], sh1[q + 2], a12);
        a03 = fmaf(wrow[q + 3], sh0[q + 3], a03);
        a13 = fmaf(wrow[q + 3], sh1[q + 3], a13);
      }
      const float z0 = (a00 + a01) + (a02 + a03);
      const float z1 = (a10 + a11) + (a12 + a13);

      const float e10 = vexp2(z0);
      const float e11 = vexp2(z1);
      const float r10 = vrcp(1.0f + e10);
      const float r11 = vrcp(1.0f + e11);
      const float act0 = fmaf(r10, act_m, act_a);
      const float act1 = fmaf(r11, act_m, act_a);

      const float ii0  = qbcast<0x00>(act0);
      const float ii1  = qbcast<0x00>(act1);
      const float ff0  = qbcast<0x55>(act0);
      const float ff1  = qbcast<0x55>(act1);
      const float ggs0 = qbcast<0xAA>(act0);
      const float ggs1 = qbcast<0xAA>(act1);
      const float oo0  = qbcast<0xFF>(act0);
      const float oo1  = qbcast<0xFF>(act1);
      const float oo20 = oo0 + oo0;
      const float oo21 = oo1 + oo1;

      cs0 = fmaf(ff0, cs0, ii0 * ggs0);
      cs1 = fmaf(ff1, cs1, ii1 * ggs1);
      const float e20 = vexp2(cs0);
      const float e21 = vexp2(cs1);
      const float r20 = vrcp(1.0f + e20);
      const float r21 = vrcp(1.0f + e21);
      const float h0  = fmaf(oo20, r20, -oo0);
      const float h1  = fmaf(oo21, r21, -oo1);

      tile0[tt * 65 + l] = h0 * wfc;
      tile1[tt * 65 + l] = h1 * wfc;

      #pragma unroll
      for (int q = 0; q < 16; ++q) {
        sh0[q] = rdlane(h0, 4 * q);
        sh1[q] = rdlane(h1, 4 * q);
      }
    }

    float s00 = bfc, s01 = 0.0f, s02 = 0.0f, s03 = 0.0f;
    float s10 = bfc, s11 = 0.0f, s12 = 0.0f, s13 = 0.0f;
    #pragma unroll
    for (int i2 = 0; i2 < 64; i2 += 4) {
      s00 += tile0[l * 65 + i2 + 0];
      s10 += tile1[l * 65 + i2 + 0];
      s01 += tile0[l * 65 + i2 + 1];
      s11 += tile1[l * 65 + i2 + 1];
      s02 += tile0[l * 65 + i2 + 2];
      s12 += tile1[l * 65 + i2 + 2];
      s03 += tile0[l * 65 + i2 + 3];
      s13 += tile1[l * 65 + i2 + 3];
    }
    ob0[blk * 64 + l] = (s00 + s01) + (s02 + s03);
    ob1[blk * 64 + l] = (s10 + s11) + (s12 + s13);
    xcur0 = xnext0;
    xcur1 = xnext1;
  }
}

extern "C" void kernel_launch(void* const* d_in, const int* in_sizes, int n_in,
                              void* d_out, int out_size, void* d_ws, size_t ws_size,
                              hipStream_t stream) {
  const float* x    = (const float*)d_in[0];
  const float* W_ih = (const float*)d_in[1];
  const float* W_hh = (const float*)d_in[2];
  const float* b_ih = (const float*)d_in[3];
  const float* b_hh = (const float*)d_in[4];
  const float* W_fc = (const float*)d_in[5];
  const float* b_fc = (const float*)d_in[6];
  float* out = (float*)d_out;
  (void)in_sizes; (void)n_in; (void)out_size; (void)d_ws; (void)ws_size;
  lstm_fused<<<NB / 2, 64, 0, stream>>>(x, W_ih, W_hh, b_ih, b_hh, W_fc, b_fc, out);
}

// Round 5
// 396.033 us; speedup vs baseline: 2.0714x; 2.0714x over previous
//
#include <hip/hip_runtime.h>
#include <hip/hip_bf16.h>

// LSTM: B=512, T=4096, I=1, H=16, O=1. f32 in/out.
// One wave per batch element (512 waves). Lane l: gate k=l&3 (i,f,g,o),
// unit j=l>>2, row r=16k+j. R3/R4: f16 packed recurrent dot —
//   h -> v_cvt_pkrtz_f16_f32(h, dpp_row_shl4(h)) packs (h_j, h_{j+1});
//   8x v_readlane of packed pairs (lanes 0,8,...,56) -> wave-uniform;
//   8x v_dot2_f32_f16 (f32 accum) replaces 16 fma + 16 readlane + 3 add.
// R4 fixes the cvt_pkrtz return-type mismatch (__fp16 vec, not _Float16 vec).

constexpr int NB = 512;   // batch
constexpr int NT = 4096;  // timesteps

typedef _Float16 half2_t __attribute__((ext_vector_type(2)));
typedef __fp16   fp16v2  __attribute__((ext_vector_type(2)));

template<int CTRL>
__device__ __forceinline__ float qbcast(float x) {
  return __int_as_float(__builtin_amdgcn_mov_dpp(__float_as_int(x), CTRL, 0xF, 0xF, true));
}
__device__ __forceinline__ float dpp_shl4(float x) {   // lane l <- lane l+4
  return __int_as_float(__builtin_amdgcn_mov_dpp(__float_as_int(x), 0x104, 0xF, 0xF, true));
}
__device__ __forceinline__ int rdlane_i(int x, int lane) {
  return __builtin_amdgcn_readlane(x, lane);
}
__device__ __forceinline__ float rdlane(float x, int lane) {
  return __int_as_float(__builtin_amdgcn_readlane(__float_as_int(x), lane));
}
__device__ __forceinline__ float vexp2(float x) {
  float r; asm("v_exp_f32 %0, %1" : "=v"(r) : "v"(x)); return r;
}
__device__ __forceinline__ float vrcp(float x) {
  float r; asm("v_rcp_f32 %0, %1" : "=v"(r) : "v"(x)); return r;
}
__device__ __forceinline__ half2_t h2_from_i(int x) {
  union { int i; half2_t h; } u; u.i = x; return u.h;
}
__device__ __forceinline__ int pack_f16(float lo, float hi) {
  union { fp16v2 v; int i; } u; u.v = __builtin_amdgcn_cvt_pkrtz(lo, hi); return u.i;
}

__global__ __launch_bounds__(64, 1) void lstm_fused(
    const float* __restrict__ x,     // [B, T]
    const float* __restrict__ W_ih,  // [64, 1]
    const float* __restrict__ W_hh,  // [64, 16]
    const float* __restrict__ b_ih,  // [64]
    const float* __restrict__ b_hh,  // [64]
    const float* __restrict__ W_fc,  // [1, 16]
    const float* __restrict__ b_fc,  // [1]
    float* __restrict__ out)         // [B, T]
{
  __shared__ float tile[64 * 65];    // [t%64][lane], stride 65: conflict-free
  const int b = blockIdx.x;
  const int l = threadIdx.x;
  const int j = l >> 2;
  const int k = l & 3;               // 0=i 1=f 2=g 3=o
  const int r = k * 16 + j;

  constexpr float LOG2E = 1.4426950408889634f;
  constexpr float K2    = -2.0f * LOG2E;       // cs = K2 * c
  const float sc = (k == 2) ? K2 : -LOG2E;

  // Recurrent weights as packed f16 pairs (pre-scaled by sc).
  half2_t w2[8];
  #pragma unroll
  for (int q = 0; q < 8; ++q) {
    w2[q][0] = (_Float16)(W_hh[r * 16 + 2 * q + 0] * sc);
    w2[q][1] = (_Float16)(W_hh[r * 16 + 2 * q + 1] * sc);
  }
  const float wx    = W_ih[r] * sc;
  const float wb    = (b_ih[r] + b_hh[r]) * sc;
  const float act_m = (k == 2) ? (2.0f * K2) : 1.0f;
  const float act_a = (k == 2) ? (-K2)       : 0.0f;
  const float wfc   = W_fc[j] * 0.25f;
  const float bfc   = b_fc[0];

  const float* xb = x + (size_t)b * NT;
  float*       ob = out + (size_t)b * NT;

  float cs = 0.0f;                   // K2-scaled cell state
  int sp[8];                         // packed f16 h-pairs, wave-uniform
  #pragma unroll
  for (int q = 0; q < 8; ++q) sp[q] = 0;

  float xcur = xb[l];

  for (int blk = 0; blk < NT / 64; ++blk) {
    float xnext = 0.0f;
    if (blk + 1 < NT / 64) xnext = xb[(blk + 1) * 64 + l];

    #pragma unroll 16
    for (int tt = 0; tt < 64; ++tt) {
      const float sx    = rdlane(xcur, tt);        // uniform x_t (off-chain)
      const float xinit = fmaf(wx, sx, wb);        // x-part + bias (off-chain)
      // z = xinit + sum_q w2[q] . h2[q]  (8 dot2, 2 accumulator chains)
      float a0 = __builtin_amdgcn_fdot2(w2[0], h2_from_i(sp[0]), xinit, false);
      float a1 = __builtin_amdgcn_fdot2(w2[1], h2_from_i(sp[1]), 0.0f,  false);
      #pragma unroll
      for (int q = 2; q < 8; q += 2) {
        a0 = __builtin_amdgcn_fdot2(w2[q + 0], h2_from_i(sp[q + 0]), a0, false);
        a1 = __builtin_amdgcn_fdot2(w2[q + 1], h2_from_i(sp[q + 1]), a1, false);
      }
      const float z   = a0 + a1;
      const float e1  = vexp2(z);
      const float r1  = vrcp(1.0f + e1);
      const float act = fmaf(r1, act_m, act_a);    // i/f/o: sigma; g: K2*tanh
      const float ii  = qbcast<0x00>(act);
      const float ff  = qbcast<0x55>(act);
      const float ggs = qbcast<0xAA>(act);         // K2*tanh(zg)
      const float oo  = qbcast<0xFF>(act);
      const float oo2 = oo + oo;                   // off-chain
      cs = fmaf(ff, cs, ii * ggs);                 // K2-scaled cell update
      const float e2 = vexp2(cs);                  // = exp(-2c)
      const float r2 = vrcp(1.0f + e2);            // = sigma(2c)
      const float h  = fmaf(oo2, r2, -oo);         // = o * tanh(c)
      tile[tt * 65 + l] = h * wfc;                 // FC partial (off-chain)
      // Pack (h_j, h_{j+1}) as f16 pair; lane 8q holds pair (h_2q, h_2q+1).
      const float hn = dpp_shl4(h);
      const int   hi = pack_f16(h, hn);
      #pragma unroll
      for (int q = 0; q < 8; ++q) sp[q] = rdlane_i(hi, 8 * q);
    }

    float s0 = bfc, s1 = 0.0f, s2 = 0.0f, s3 = 0.0f;
    #pragma unroll
    for (int i2 = 0; i2 < 64; i2 += 4) {
      s0 += tile[l * 65 + i2 + 0];
      s1 += tile[l * 65 + i2 + 1];
      s2 += tile[l * 65 + i2 + 2];
      s3 += tile[l * 65 + i2 + 3];
    }
    ob[blk * 64 + l] = (s0 + s1) + (s2 + s3);
    xcur = xnext;
  }
}

extern "C" void kernel_launch(void* const* d_in, const int* in_sizes, int n_in,
                              void* d_out, int out_size, void* d_ws, size_t ws_size,
                              hipStream_t stream) {
  const float* x    = (const float*)d_in[0];
  const float* W_ih = (const float*)d_in[1];
  const float* W_hh = (const float*)d_in[2];
  const float* b_ih = (const float*)d_in[3];
  const float* b_hh = (const float*)d_in[4];
  const float* W_fc = (const float*)d_in[5];
  const float* b_fc = (const float*)d_in[6];
  float* out = (float*)d_out;
  (void)in_sizes; (void)n_in; (void)out_size; (void)d_ws; (void)ws_size;
  lstm_fused<<<NB, 64, 0, stream>>>(x, W_ih, W_hh, b_ih, b_hh, W_fc, b_fc, out);
}